// Round 5
// baseline (264.752 us; speedup 1.0000x reference)
//
#include <hip/hip_runtime.h>

// Sinkhorn, B=8 N=1024 C=64, T=2, eps=0.1, 20 iters, scale=1e-3.
// Only batch 7 contributes (reference returns losses[-1]).
// Row/col normalize scan == diagonal scaling: u = 1/(K v), v = 1/(K^T u);
// loss = sum_ij u_i K_ij v_j W_ij with W_ij = -0.1*log(K_ij).
//
// Persistent kernel, SINGLE launch. Barrier v3: slot-array + master-broadcast,
// zero atomic RMWs (round-4's leaf fetch_adds serialized at the coherence
// point -> ~4.3us/barrier). Arrival = one relaxed sc0sc1 store to slot[bid];
// master wave gathers 64 slots in ONE coalesced bypass load + ballot, stores
// monotone epoch to a go-line; cohort polls go. Iteration barriers span only
// 64 blocks (blocks 64..255 arrive-and-exit after K build).
// Slots start as 0xAA poison (negative int) -> no init kernel needed.

static constexpr int N  = 1024;
static constexpr int C  = 64;
static constexpr int NB = 256;   // launch width (phases 1-2)
static constexpr int NC = 64;    // iteration cohort

// ws layout (floats); harness ws is poisoned 0xAA before every call
static constexpr int WS_XS   = 0;          // softmax(y_s[7]/2) : 1024*64
static constexpr int WS_YS   = 65536;      // softmax(y_t[7]/2) : 1024*64
static constexpr int WS_K    = 131072;     // K    : 1024*1024
static constexpr int WS_KT   = 1179648;    // K^T  : 1024*1024
static constexpr int WS_U    = 2228224;    // u : 1024
static constexpr int WS_V    = 2229248;    // v : 1024
static constexpr int WS_P    = 2230272;    // cohort partials : 64
static constexpr int WS_SLOT = 2230528;    // 256 arrival slots (int)
static constexpr int WS_GO   = 2230848;    // go epoch (int), own cache line

__device__ __forceinline__ void ast(float* p, float v) {
    __hip_atomic_store(p, v, __ATOMIC_RELAXED, __HIP_MEMORY_SCOPE_SYSTEM);
}
__device__ __forceinline__ float ald(const float* p) {
    return __hip_atomic_load(p, __ATOMIC_RELAXED, __HIP_MEMORY_SCOPE_SYSTEM);
}
__device__ __forceinline__ void asti(int* p, int v) {
    __hip_atomic_store(p, v, __ATOMIC_RELAXED, __HIP_MEMORY_SCOPE_SYSTEM);
}
__device__ __forceinline__ int aldi(const int* p) {
    return __hip_atomic_load(p, __ATOMIC_RELAXED, __HIP_MEMORY_SCOPE_SYSTEM);
}

__device__ __forceinline__ float wsum(float v) {
    #pragma unroll
    for (int o = 32; o > 0; o >>= 1) v += __shfl_down(v, o, 64);
    return v;
}
__device__ __forceinline__ float wmax(float v) {
    #pragma unroll
    for (int o = 32; o > 0; o >>= 1) v = fmaxf(v, __shfl_down(v, o, 64));
    return v;
}

__global__ void __launch_bounds__(256)
sink_k(const float* __restrict__ ysrc, const float* __restrict__ ytrc,
       float* __restrict__ out, float* __restrict__ ws)
{
    // sx 32*64=2048 | sy 32*68=2176 | kt 32*33=1056 -> 5280 floats (21.1 KB)
    __shared__ float smem[5280];
    const int tid  = threadIdx.x;
    const int bid  = blockIdx.x;
    const int wid  = tid >> 6;
    const int lane = tid & 63;
    int* slot = (int*)(ws + WS_SLOT);
    int* go   = (int*)(ws + WS_GO);
    int ep = 0;

    // Slot/broadcast barrier. __syncthreads() makes every wave drain vmcnt,
    // so all prior sc0sc1 payload stores are at the coherence point before
    // the arrival store. Epochs are monotone (1,2,...); 0xAA poison < 1.
    auto gbar = [&](int nb, bool wait) {
        __syncthreads();
        ++ep;
        if (bid == 0) {
            if (wid == 0) {
                if (lane == 0) asti(&slot[0], ep);
                int guard = 0;
                for (;;) {
                    int mn = 0x7fffffff;
                    for (int k = lane; k < nb; k += 64)
                        mn = min(mn, aldi(&slot[k]));
                    if (__ballot(mn >= ep) == 0xFFFFFFFFFFFFFFFFULL) break;
                    __builtin_amdgcn_s_sleep(2);
                    if (++guard > (1 << 22)) break;   // bailout: no hang
                }
                if (lane == 0) asti(go, ep);
            }
            __syncthreads();
        } else {
            if (tid == 0) {
                asti(&slot[bid], ep);
                if (wait) {
                    int guard = 0;
                    while (aldi(go) < ep) {
                        __builtin_amdgcn_s_sleep(2);
                        if (++guard > (1 << 22)) break;
                    }
                }
            }
            __syncthreads();
        }
    };

    // ---- phase 1: softmax over N (dim=1), batch 7; blocks 0..127.
    //      block 255 (idle here) writes v := 1.
    if (bid < 2 * C) {
        const float* src = ((bid < C) ? ysrc : ytrc) + 7 * N * C;
        float* dst = ws + ((bid < C) ? WS_XS : WS_YS);
        const int c = bid & (C - 1);
        float vals[4];
        float m = -1e30f;
        #pragma unroll
        for (int q = 0; q < 4; ++q) {
            vals[q] = src[(q * 256 + tid) * C + c] * 0.5f;   // y/T, T=2
            m = fmaxf(m, vals[q]);
        }
        m = wmax(m);
        if (lane == 0) smem[wid] = m;
        __syncthreads();
        m = fmaxf(fmaxf(smem[0], smem[1]), fmaxf(smem[2], smem[3]));
        float s = 0.f;
        #pragma unroll
        for (int q = 0; q < 4; ++q) { vals[q] = expf(vals[q] - m); s += vals[q]; }
        s = wsum(s);
        __syncthreads();
        if (lane == 0) smem[wid] = s;
        __syncthreads();
        s = smem[0] + smem[1] + smem[2] + smem[3];
        const float inv = 1.0f / s;
        #pragma unroll
        for (int q = 0; q < 4; ++q)
            ast(&dst[(q * 256 + tid) * C + c], vals[q] * inv);
    } else if (bid == 255) {
        for (int i = tid; i < N; i += 256) ast(&ws[WS_V + i], 1.0f);
    }
    gbar(NB, true);                                   // ep = 1

    // ---- phase 2: K_ij = exp(-10 * sum_c |x_ic - y_jc|) and K^T; all blocks
    {
        float* xs  = ws + WS_XS;
        float* ysm = ws + WS_YS;
        float* K   = ws + WS_K;
        float* KT  = ws + WS_KT;
        float* sx = smem;          // [32][64]
        float* sy = smem + 2048;   // [32][68]
        float* kt = smem + 4224;   // [32][33]
        #pragma unroll 1
        for (int t = 0; t < 4; ++t) {
            const int tt = bid * 4 + t;
            const int ti = tt >> 5, tj = tt & 31;
            __syncthreads();
            for (int k = tid; k < 2048; k += 256) sx[k] = xs[ti * 2048 + k];
            for (int k = tid; k < 2048; k += 256)
                sy[(k >> 6) * 68 + (k & 63)] = ysm[tj * 2048 + k];
            __syncthreads();
            float kv[4];
            #pragma unroll
            for (int q = 0; q < 4; ++q) {
                const int idx = q * 256 + tid;
                const int il = idx >> 5, jl = idx & 31;
                const float4* sx4 = (const float4*)(sx + il * 64);
                const float4* sy4 = (const float4*)(sy + jl * 68);
                float a = 0.f;
                #pragma unroll
                for (int c4 = 0; c4 < 16; ++c4) {
                    const float4 xa = sx4[c4], yb = sy4[c4];
                    a += fabsf(xa.x - yb.x) + fabsf(xa.y - yb.y)
                       + fabsf(xa.z - yb.z) + fabsf(xa.w - yb.w);
                }
                kv[q] = expf(-10.0f * a);                      // exp(-W/eps)
                ast(&K[(ti * 32 + il) * N + tj * 32 + jl], kv[q]);
            }
            __syncthreads();
            #pragma unroll
            for (int q = 0; q < 4; ++q) {
                const int idx = q * 256 + tid;
                kt[(idx >> 5) * 33 + (idx & 31)] = kv[q];
            }
            __syncthreads();
            #pragma unroll
            for (int q = 0; q < 4; ++q) {
                const int idx = q * 256 + tid;
                const int jl = idx >> 5, il = idx & 31;
                ast(&KT[(tj * 32 + jl) * N + ti * 32 + il], kt[il * 33 + jl]);
            }
        }
    }
    gbar(NB, bid < NC);                               // ep = 2
    if (bid >= NC) return;                            // cohort continues alone

    // ---- phase 3: 20 iterations; wave owns 4 contiguous rows ----
    const int w4 = (bid * 4 + wid) * 4;               // first of 4 rows
    const float4* K4  = (const float4*)(ws + WS_K);
    const float4* KT4 = (const float4*)(ws + WS_KT);
    float* u = ws + WS_U;
    float* v = ws + WS_V;
    const float4* sv4 = (const float4*)smem;
    #pragma unroll 1
    for (int it = 0; it < 20; ++it) {
        {   // stage v -> LDS (coherence-point reads; L2 copy may be stale)
            float t0 = ald(&v[tid]),       t1 = ald(&v[tid + 256]);
            float t2 = ald(&v[tid + 512]), t3 = ald(&v[tid + 768]);
            smem[tid] = t0; smem[tid + 256] = t1;
            smem[tid + 512] = t2; smem[tid + 768] = t3;
        }
        __syncthreads();
        float acc[4];
        #pragma unroll
        for (int q = 0; q < 4; ++q) {
            const float4* Kr = K4 + (size_t)(w4 + q) * 256;
            float a = 0.f;
            #pragma unroll
            for (int j = lane; j < 256; j += 64) {
                const float4 kk = Kr[j]; const float4 vv = sv4[j];
                a += kk.x * vv.x + kk.y * vv.y + kk.z * vv.z + kk.w * vv.w;
            }
            acc[q] = wsum(a);
        }
        if (lane == 0) {
            #pragma unroll
            for (int q = 0; q < 4; ++q) ast(&u[w4 + q], 1.0f / acc[q]);
        }
        gbar(NC, true);
        {   // stage u -> LDS
            float t0 = ald(&u[tid]),       t1 = ald(&u[tid + 256]);
            float t2 = ald(&u[tid + 512]), t3 = ald(&u[tid + 768]);
            smem[tid] = t0; smem[tid + 256] = t1;
            smem[tid + 512] = t2; smem[tid + 768] = t3;
        }
        __syncthreads();
        #pragma unroll
        for (int q = 0; q < 4; ++q) {
            const float4* Kr = KT4 + (size_t)(w4 + q) * 256;
            float a = 0.f;
            #pragma unroll
            for (int j = lane; j < 256; j += 64) {
                const float4 kk = Kr[j]; const float4 uu = sv4[j];
                a += kk.x * uu.x + kk.y * uu.y + kk.z * uu.z + kk.w * uu.w;
            }
            acc[q] = wsum(a);
        }
        if (lane == 0) {
            #pragma unroll
            for (int q = 0; q < 4; ++q) ast(&v[w4 + q], 1.0f / acc[q]);
        }
        gbar(NC, true);
    }

    // ---- phase 4: partial[bid] = sum over 16 rows of u_i K_ij v_j log K_ij
    {
        {   // stage final v -> LDS
            float t0 = ald(&v[tid]),       t1 = ald(&v[tid + 256]);
            float t2 = ald(&v[tid + 512]), t3 = ald(&v[tid + 768]);
            smem[tid] = t0; smem[tid + 256] = t1;
            smem[tid + 512] = t2; smem[tid + 768] = t3;
        }
        __syncthreads();
        float blocksum = 0.f;
        #pragma unroll
        for (int q = 0; q < 4; ++q) {
            const float* Kr = ws + WS_K + (size_t)(w4 + q) * N;
            float a = 0.f;
            for (int j = lane; j < N; j += 64) {
                const float k = Kr[j];
                a += k * smem[j] * logf(k);
            }
            a = wsum(a);
            if (lane == 0) blocksum += ald(&u[w4 + q]) * a;
        }
        if (lane == 0) smem[1028 + wid] = blocksum;
        __syncthreads();
        if (tid == 0)
            ast(&ws[WS_P + bid],
                smem[1028] + smem[1029] + smem[1030] + smem[1031]);
    }
    gbar(NC, true);

    // ---- phase 5: block 0 wave 0 folds 64 partials -> scalar out ----
    if (bid == 0 && wid == 0) {
        float a = ald(&ws[WS_P + lane]);    // NC == 64 == wave width
        a = wsum(a);
        if (lane == 0) out[0] = -1e-4f * a;  // 1e-3 * (-0.1)
    }
}

extern "C" void kernel_launch(void* const* d_in, const int* in_sizes, int n_in,
                              void* d_out, int out_size, void* d_ws, size_t ws_size,
                              hipStream_t stream) {
    const float* y_s = (const float*)d_in[0];
    const float* y_t = (const float*)d_in[1];
    float* out = (float*)d_out;
    float* ws  = (float*)d_ws;
    sink_k<<<dim3(NB), dim3(256), 0, stream>>>(y_s, y_t, out, ws);
}

// Round 6
// 216.286 us; speedup vs baseline: 1.2241x; 1.2241x over previous
//
#include <hip/hip_runtime.h>

// Sinkhorn, B=8 N=1024 C=64, T=2, eps=0.1, 20 iters, scale=1e-3.
// Only batch 7 contributes (reference returns losses[-1]).
// Row/col normalize scan == diagonal scaling: u = 1/(K v), v = 1/(K^T u);
// loss = sum_ij u_i K_ij v_j W_ij with W_ij = -0.1*log(K_ij).
//
// BARRIER-FREE persistent kernel. Rounds 3-5 showed any centralized barrier
// costs 4-9us (3 serialized coherence-point hops). Here every cross-block
// value is a self-flagging tagged word: u64 = (epoch<<32)|float_bits, stored
// and polled with relaxed system-scope (sc0sc1) atomics -> sync cost = ONE
// store->visible hop. Tag+value share one atomic word, so no ordering
// machinery is needed. Dataflow deadlock-free: v epoch e+1 is written only
// after full u epoch e was read (and vice versa).

typedef unsigned long long u64;

static constexpr int N  = 1024;
static constexpr int C  = 64;
static constexpr int NB = 256;   // 1 block/CU, all co-resident

// float-offsets into ws (all u64 arrays 8B-aligned)
static constexpr int WS_K   = 0;          // K  : 1024*1024 f32
static constexpr int WS_KT  = 1048576;    // KT : 1024*1024 f32
static constexpr int WS_U2  = 2097152;    // u64[1024] tagged u
static constexpr int WS_V2  = 2099200;    // u64[1024] tagged v
static constexpr int WS_MS  = 2101248;    // u64[64] tagged col max, y_s
static constexpr int WS_SS  = 2101376;    // u64[64] tagged col sum, y_s
static constexpr int WS_MT  = 2101504;    // u64[64] tagged col max, y_t
static constexpr int WS_ST  = 2101632;    // u64[64] tagged col sum, y_t
static constexpr int WS_P2  = 2101760;    // u64[256] tagged loss partials
static constexpr int WS_D   = 2102272;    // int[256] phase-2 done flags

__device__ __forceinline__ void ast(float* p, float v) {
    __hip_atomic_store(p, v, __ATOMIC_RELAXED, __HIP_MEMORY_SCOPE_SYSTEM);
}
__device__ __forceinline__ void ast64(u64* p, u64 v) {
    __hip_atomic_store(p, v, __ATOMIC_RELAXED, __HIP_MEMORY_SCOPE_SYSTEM);
}
__device__ __forceinline__ u64 ald64(const u64* p) {
    return __hip_atomic_load(p, __ATOMIC_RELAXED, __HIP_MEMORY_SCOPE_SYSTEM);
}
__device__ __forceinline__ void asti(int* p, int v) {
    __hip_atomic_store(p, v, __ATOMIC_RELAXED, __HIP_MEMORY_SCOPE_SYSTEM);
}
__device__ __forceinline__ int aldi(const int* p) {
    return __hip_atomic_load(p, __ATOMIC_RELAXED, __HIP_MEMORY_SCOPE_SYSTEM);
}
__device__ __forceinline__ u64 pk(unsigned e, float f) {
    return ((u64)e << 32) | (u64)__float_as_uint(f);
}
__device__ __forceinline__ unsigned tg(u64 x) { return (unsigned)(x >> 32); }
__device__ __forceinline__ float    vl(u64 x) { return __uint_as_float((unsigned)x); }

__device__ __forceinline__ float wsum(float v) {
    #pragma unroll
    for (int o = 32; o > 0; o >>= 1) v += __shfl_down(v, o, 64);
    return v;
}
__device__ __forceinline__ float wmax(float v) {
    #pragma unroll
    for (int o = 32; o > 0; o >>= 1) v = fmaxf(v, __shfl_down(v, o, 64));
    return v;
}

__global__ void __launch_bounds__(256)
sink_k(const float* __restrict__ ysrc, const float* __restrict__ ytrc,
       float* __restrict__ out, float* __restrict__ ws)
{
    // sx 32*64=2048 | sy 32*68=2176 | kt 32*33=1056 -> 5280 floats (21.1 KB)
    __shared__ float smem[5280];
    const int tid  = threadIdx.x;
    const int bid  = blockIdx.x;
    const int wid  = tid >> 6;
    const int lane = tid & 63;
    u64* U2 = (u64*)(ws + WS_U2);
    u64* V2 = (u64*)(ws + WS_V2);
    u64* MS = (u64*)(ws + WS_MS);
    u64* SS = (u64*)(ws + WS_SS);
    u64* MT = (u64*)(ws + WS_MT);
    u64* ST = (u64*)(ws + WS_ST);
    u64* P2 = (u64*)(ws + WS_P2);
    int* DF = (int*)(ws + WS_D);
    float* K  = ws + WS_K;
    float* KT = ws + WS_KT;
    const float* ys7 = ysrc + 7 * N * C;
    const float* yt7 = ytrc + 7 * N * C;

    // ---- phase 1: per-column softmax stats (max, sum), batch 7 ----
    // blocks 0..127: one column each; publish tagged (m, s).
    // blocks 128..131: publish initial v = 1 (tagged epoch 1).
    if (bid < 2 * C) {
        const float* src = (bid < C) ? ys7 : yt7;
        const int c = bid & (C - 1);
        float vals[4];
        float m = -1e30f;
        #pragma unroll
        for (int q = 0; q < 4; ++q) {
            vals[q] = src[(q * 256 + tid) * C + c] * 0.5f;   // y/T, T=2
            m = fmaxf(m, vals[q]);
        }
        m = wmax(m);
        if (lane == 0) smem[wid] = m;
        __syncthreads();
        m = fmaxf(fmaxf(smem[0], smem[1]), fmaxf(smem[2], smem[3]));
        float s = 0.f;
        #pragma unroll
        for (int q = 0; q < 4; ++q) s += expf(vals[q] - m);
        s = wsum(s);
        __syncthreads();
        if (lane == 0) smem[wid] = s;
        __syncthreads();
        s = smem[0] + smem[1] + smem[2] + smem[3];
        if (tid == 0) {
            u64* Mo = (bid < C) ? MS : MT;
            u64* So = (bid < C) ? SS : ST;
            ast64(&Mo[c], pk(1u, m));
            ast64(&So[c], pk(1u, s));
        }
        __syncthreads();          // smem reused in phase 2
    } else if (bid < 132) {
        ast64(&V2[(bid - 128) * 256 + tid], pk(1u, 1.0f));
    }

    // ---- phase 2: poll softmax stats, build K and KT (4 32x32 tiles/block)
    float mxs, isx, mys, isy;
    {
        const int c = tid & 63;
        u64 a0 = ald64(&MS[c]), a1 = ald64(&SS[c]);
        u64 a2 = ald64(&MT[c]), a3 = ald64(&ST[c]);
        int g = 0;
        while (tg(a0) != 1u || tg(a1) != 1u || tg(a2) != 1u || tg(a3) != 1u) {
            if (tg(a0) != 1u) a0 = ald64(&MS[c]);
            if (tg(a1) != 1u) a1 = ald64(&SS[c]);
            if (tg(a2) != 1u) a2 = ald64(&MT[c]);
            if (tg(a3) != 1u) a3 = ald64(&ST[c]);
            __builtin_amdgcn_s_sleep(1);
            if (++g > (1 << 22)) break;     // bailout: no hang
        }
        mxs = vl(a0); isx = 1.0f / vl(a1);
        mys = vl(a2); isy = 1.0f / vl(a3);
    }
    {
        float* sx = smem;          // [32][64]
        float* sy = smem + 2048;   // [32][68]
        float* kt = smem + 4224;   // [32][33]
        #pragma unroll 1
        for (int t = 0; t < 4; ++t) {
            const int tt = bid * 4 + t;
            const int ti = tt >> 5, tj = tt & 31;
            __syncthreads();
            // softmax recompute on the fly: col of element k is tid&63 ==
            // the c whose (m,s) this thread polled. Bitwise-identical to
            // materialized softmax (same expf inputs, same 1/s factor).
            for (int k = tid; k < 2048; k += 256)
                sx[k] = expf(ys7[ti * 2048 + k] * 0.5f - mxs) * isx;
            for (int k = tid; k < 2048; k += 256)
                sy[(k >> 6) * 68 + (k & 63)] =
                    expf(yt7[tj * 2048 + k] * 0.5f - mys) * isy;
            __syncthreads();
            float kv[4];
            #pragma unroll
            for (int q = 0; q < 4; ++q) {
                const int idx = q * 256 + tid;
                const int il = idx >> 5, jl = idx & 31;
                const float4* sx4 = (const float4*)(sx + il * 64);
                const float4* sy4 = (const float4*)(sy + jl * 68);
                float a = 0.f;
                #pragma unroll
                for (int c4 = 0; c4 < 16; ++c4) {
                    const float4 xa = sx4[c4], yb = sy4[c4];
                    a += fabsf(xa.x - yb.x) + fabsf(xa.y - yb.y)
                       + fabsf(xa.z - yb.z) + fabsf(xa.w - yb.w);
                }
                kv[q] = expf(-10.0f * a);                      // exp(-W/eps)
                ast(&K[(ti * 32 + il) * N + tj * 32 + jl], kv[q]);
            }
            __syncthreads();
            #pragma unroll
            for (int q = 0; q < 4; ++q) {
                const int idx = q * 256 + tid;
                kt[(idx >> 5) * 33 + (idx & 31)] = kv[q];
            }
            __syncthreads();
            #pragma unroll
            for (int q = 0; q < 4; ++q) {
                const int idx = q * 256 + tid;
                const int jl = idx >> 5, il = idx & 31;
                ast(&KT[(tj * 32 + jl) * N + ti * 32 + il], kt[il * 33 + jl]);
            }
        }
    }
    __syncthreads();               // drains vmcnt: K/KT stores are at the
    if (tid == 0) asti(&DF[bid], 1);   // coherence point before this flag

    // ---- phase 3 pre: poll the 40 producer flags for our K/KT rows ----
    // Our rows r = 4*bid..4*bid+3 share strip S = r>>5 = bid>>3.
    // K rows written by blocks [8S, 8S+8); KT rows by blocks {8*ti + (S>>2)}.
    {
        const int S = bid >> 3;
        int idx = -1;
        if (lane < 8) idx = S * 8 + lane;
        else if (lane < 40) idx = (lane - 8) * 8 + (S >> 2);
        int g = 0;
        for (;;) {
            int f = (idx >= 0) ? aldi(&DF[idx]) : 1;
            if (__ballot(f < 1) == 0ULL) break;
            __builtin_amdgcn_s_sleep(1);
            if (++g > (1 << 22)) break;
        }
    }
    __syncthreads();

    // ---- phase 3: 20 iterations, barrier-free tagged dataflow ----
    const int r = bid * 4 + wid;                   // wave owns one row
    const float4* Kr4  = (const float4*)(K  + (size_t)r * N);
    const float4* KTr4 = (const float4*)(KT + (size_t)r * N);
    const float4* sv4  = (const float4*)smem;
    float u_keep = 0.f;

    // poll 4 tagged entries/thread into LDS; exact-epoch match (tags never
    // skip: epoch e+1 of a vector requires full opposite-vector epoch e read)
    auto stage = [&](u64* src, unsigned e) {
        u64 x0 = ald64(&src[tid]),       x1 = ald64(&src[tid + 256]);
        u64 x2 = ald64(&src[tid + 512]), x3 = ald64(&src[tid + 768]);
        int g = 0;
        while (tg(x0) != e || tg(x1) != e || tg(x2) != e || tg(x3) != e) {
            if (tg(x0) != e) x0 = ald64(&src[tid]);
            if (tg(x1) != e) x1 = ald64(&src[tid + 256]);
            if (tg(x2) != e) x2 = ald64(&src[tid + 512]);
            if (tg(x3) != e) x3 = ald64(&src[tid + 768]);
            __builtin_amdgcn_s_sleep(1);
            if (++g > (1 << 22)) break;
        }
        smem[tid]       = vl(x0); smem[tid + 256] = vl(x1);
        smem[tid + 512] = vl(x2); smem[tid + 768] = vl(x3);
        __syncthreads();
    };

    #pragma unroll 1
    for (int it = 0; it < 20; ++it) {
        stage(V2, (unsigned)(it + 1));
        float a = 0.f;
        #pragma unroll
        for (int k = 0; k < 4; ++k) {
            const int j = lane + 64 * k;
            const float4 kk = Kr4[j]; const float4 vv = sv4[j];
            a += kk.x * vv.x + kk.y * vv.y + kk.z * vv.z + kk.w * vv.w;
        }
        a = wsum(a);
        if (lane == 0) {
            u_keep = 1.0f / a;
            ast64(&U2[r], pk((unsigned)(it + 1), u_keep));
        }
        __syncthreads();               // smem v-reads done before u staging
        stage(U2, (unsigned)(it + 1));
        a = 0.f;
        #pragma unroll
        for (int k = 0; k < 4; ++k) {
            const int j = lane + 64 * k;
            const float4 kk = KTr4[j]; const float4 uu = sv4[j];
            a += kk.x * uu.x + kk.y * uu.y + kk.z * uu.z + kk.w * uu.w;
        }
        a = wsum(a);
        if (lane == 0) ast64(&V2[r], pk((unsigned)(it + 2), 1.0f / a));
        __syncthreads();               // smem u-reads done before next stage
    }

    // ---- phase 4: partial[bid] = sum over 4 rows of u_i K_ij v_j log K_ij
    {
        stage(V2, 21u);                // final v
        const float* Kr = K + (size_t)r * N;
        float a = 0.f;
        for (int j = lane; j < N; j += 64) {
            const float kx = Kr[j];
            a += kx * smem[j] * logf(kx);
        }
        a = wsum(a);
        if (lane == 0) smem[1028 + wid] = u_keep * a;   // u_keep = u[r] tag 20
        __syncthreads();
        if (tid == 0)
            ast64(&P2[bid], pk(1u, smem[1028] + smem[1029]
                                 + smem[1030] + smem[1031]));
    }

    // ---- phase 5: block 0 polls 256 tagged partials -> scalar out ----
    if (bid == 0) {
        u64 x = ald64(&P2[tid]);
        int g = 0;
        while (tg(x) != 1u) {
            x = ald64(&P2[tid]);
            __builtin_amdgcn_s_sleep(1);
            if (++g > (1 << 22)) break;
        }
        float a = vl(x);
        a = wsum(a);
        __syncthreads();
        if (lane == 0) smem[wid] = a;
        __syncthreads();
        if (tid == 0)
            out[0] = -1e-4f * (smem[0] + smem[1] + smem[2] + smem[3]); // 1e-3*(-0.1)
    }
}

extern "C" void kernel_launch(void* const* d_in, const int* in_sizes, int n_in,
                              void* d_out, int out_size, void* d_ws, size_t ws_size,
                              hipStream_t stream) {
    const float* y_s = (const float*)d_in[0];
    const float* y_t = (const float*)d_in[1];
    float* out = (float*)d_out;
    float* ws  = (float*)d_ws;
    sink_k<<<dim3(NB), dim3(256), 0, stream>>>(y_s, y_t, out, ws);
}